// Round 1
// baseline (373.571 us; speedup 1.0000x reference)
//
#include <hip/hip_runtime.h>

#define N_NODES 50000
#define N_EDGES 600000

typedef short bf16x8 __attribute__((ext_vector_type(8)));
typedef float f32x4  __attribute__((ext_vector_type(4)));
typedef unsigned short u16x8 __attribute__((ext_vector_type(8)));
typedef unsigned short u16x4 __attribute__((ext_vector_type(4)));

// ---------------- bf16 helpers (RNE) ----------------
__device__ inline ushort rne_bf16(float a) {
    union { float f; unsigned u; } v; v.f = a;
    return (ushort)((v.u + 0x7FFFu + ((v.u >> 16) & 1u)) >> 16);
}
__device__ inline float bf16_to_f32(ushort h) {
    return __uint_as_float((unsigned)h << 16);
}
__device__ inline void split_bf16(float a, ushort& hi, ushort& lo) {
    hi = rne_bf16(a);
    float hv = bf16_to_f32(hi);
    lo = rne_bf16(a - hv);
}

// ---------------- CSR build ----------------

__global__ void count_deg_kernel(const int* __restrict__ dst, int* __restrict__ deg, int ne) {
    int e = blockIdx.x * blockDim.x + threadIdx.x;
    if (e < ne) atomicAdd(&deg[dst[e]], 1);
}

__global__ __launch_bounds__(256) void block_sums_kernel(const int* __restrict__ deg,
                                                         int* __restrict__ bsum, int n) {
    __shared__ int s[256];
    int t = threadIdx.x;
    int i = blockIdx.x * 256 + t;
    s[t] = (i < n) ? deg[i] : 0;
    __syncthreads();
    #pragma unroll
    for (int d = 128; d > 0; d >>= 1) {
        if (t < d) s[t] += s[t + d];
        __syncthreads();
    }
    if (t == 0) bsum[blockIdx.x] = s[0];
}

__global__ __launch_bounds__(256) void scan_bsums_kernel(const int* __restrict__ bsum,
                                                         int* __restrict__ base, int nb,
                                                         int* __restrict__ off, int n) {
    __shared__ int s[256];
    int t = threadIdx.x;
    int v = (t < nb) ? bsum[t] : 0;
    s[t] = v;
    __syncthreads();
    #pragma unroll
    for (int d = 1; d < 256; d <<= 1) {
        int x = (t >= d) ? s[t - d] : 0;
        __syncthreads();
        s[t] += x;
        __syncthreads();
    }
    if (t < nb) base[t] = s[t] - v;
    if (t == 255) off[n] = s[255];
}

__global__ __launch_bounds__(256) void scatter_offsets_kernel(const int* __restrict__ deg,
                                                              const int* __restrict__ base,
                                                              int* __restrict__ off,
                                                              int* __restrict__ cur, int n) {
    __shared__ int s[256];
    int t = threadIdx.x;
    int i = blockIdx.x * 256 + t;
    int v = (i < n) ? deg[i] : 0;
    s[t] = v;
    __syncthreads();
    #pragma unroll
    for (int d = 1; d < 256; d <<= 1) {
        int x = (t >= d) ? s[t - d] : 0;
        __syncthreads();
        s[t] += x;
        __syncthreads();
    }
    if (i < n) {
        int excl = s[t] - v + base[blockIdx.x];
        off[i] = excl;
        cur[i] = excl;
    }
}

__global__ void fill_csr_kernel(const int* __restrict__ src, const int* __restrict__ dst,
                                int* __restrict__ cur, int* __restrict__ ssrc, int ne) {
    int e = blockIdx.x * blockDim.x + threadIdx.x;
    if (e < ne) {
        int p = atomicAdd(&cur[dst[e]], 1);
        ssrc[p] = src[e];
    }
}

// ---------------- weight pre-convert ----------------
__global__ void convert_w_kernel(const float* __restrict__ Ws, const float* __restrict__ Wn,
                                 int dout, ushort* __restrict__ Bth, ushort* __restrict__ Btl) {
    int n = blockIdx.x;
    int k = threadIdx.x;
    float w = (n < dout) ? Ws[(long)k * dout + n] : Wn[(long)k * dout + (n - dout)];
    ushort hi, lo;
    split_bf16(w, hi, lo);
    Bth[n * 128 + k] = hi;
    Btl[n * 128 + k] = lo;
}

// ---------------- split-bf16 MFMA dual GEMM, wave-independent (no LDS) ----------------
// S = A@Ws + bias (fp32), T = A@Wn (stored bf16 for the cheap gather).
// A-fragment for mfma_f32_16x16x32_bf16 is row=lane&15, k=quad*8+j -> lane loads its
// 8 contiguous fp32 directly from global and splits to hi/lo bf16 in registers.

#define KDIM 128
#define BKC  32

__device__ inline void load_split_a(const float* __restrict__ ap, bf16x8& ah, bf16x8& al) {
    float4 a0 = *(const float4*)ap;
    float4 a1 = *(const float4*)(ap + 4);
    float f[8] = {a0.x, a0.y, a0.z, a0.w, a1.x, a1.y, a1.z, a1.w};
    #pragma unroll
    for (int i = 0; i < 8; ++i) {
        ushort h, l;
        split_bf16(f[i], h, l);
        ah[i] = (short)h;
        al[i] = (short)l;
    }
}

// Wide: dout=128 dual (256 cols). Block = 32 rows x 256 cols, wave = 32 rows x 64 cols.
__global__ __launch_bounds__(256) void gemm_mfma_wide(
    const float* __restrict__ A,
    const ushort* __restrict__ Bth, const ushort* __restrict__ Btl,
    const float* __restrict__ bias,
    float* __restrict__ S, ushort* __restrict__ T, int M)
{
    const int tid = threadIdx.x;
    const int wave = tid >> 6;
    const int lane = tid & 63;
    const int lane16 = lane & 15;
    const int quad = lane >> 4;
    const int bm = blockIdx.x * 32;
    const int colbase = wave * 64;

    const int row0 = bm + lane16;
    const int row1 = row0 + 16;
    const bool ok0 = row0 < M;
    const bool ok1 = row1 < M;

    f32x4 acc[2][4] = {};

    #pragma unroll 2
    for (int c = 0; c < 4; ++c) {
        const int k0 = c * BKC + quad * 8;

        bf16x8 ah0 = {}, al0 = {}, ah1 = {}, al1 = {};
        if (ok0) load_split_a(A + (long)row0 * KDIM + k0, ah0, al0);
        if (ok1) load_split_a(A + (long)row1 * KDIM + k0, ah1, al1);

        #pragma unroll
        for (int ct = 0; ct < 4; ++ct) {
            const long boff = (long)(colbase + 16 * ct + lane16) * KDIM + k0;
            bf16x8 bh = *(const bf16x8*)(Bth + boff);
            bf16x8 bl = *(const bf16x8*)(Btl + boff);
            acc[0][ct] = __builtin_amdgcn_mfma_f32_16x16x32_bf16(ah0, bh, acc[0][ct], 0, 0, 0);
            acc[0][ct] = __builtin_amdgcn_mfma_f32_16x16x32_bf16(ah0, bl, acc[0][ct], 0, 0, 0);
            acc[0][ct] = __builtin_amdgcn_mfma_f32_16x16x32_bf16(al0, bh, acc[0][ct], 0, 0, 0);
            acc[1][ct] = __builtin_amdgcn_mfma_f32_16x16x32_bf16(ah1, bh, acc[1][ct], 0, 0, 0);
            acc[1][ct] = __builtin_amdgcn_mfma_f32_16x16x32_bf16(ah1, bl, acc[1][ct], 0, 0, 0);
            acc[1][ct] = __builtin_amdgcn_mfma_f32_16x16x32_bf16(al1, bh, acc[1][ct], 0, 0, 0);
        }
    }

    #pragma unroll
    for (int ct = 0; ct < 4; ++ct) {
        int col = colbase + 16 * ct + lane16;
        bool toS = col < 128;
        float bv = toS ? bias[col] : 0.f;
        int tcol = toS ? col : col - 128;
        #pragma unroll
        for (int r = 0; r < 2; ++r) {
            #pragma unroll
            for (int i = 0; i < 4; ++i) {
                int row = bm + 16 * r + quad * 4 + i;
                if (row < M) {
                    if (toS) S[(long)row * 128 + tcol] = acc[r][ct][i] + bv;
                    else     T[(long)row * 128 + tcol] = rne_bf16(acc[r][ct][i]);
                }
            }
        }
    }
}

// Narrow: dout=40 dual (80 cols). Block = 64 rows, wave = 16 rows x 80 cols (5 ct).
__global__ __launch_bounds__(256) void gemm_mfma_narrow(
    const float* __restrict__ A,
    const ushort* __restrict__ Bth, const ushort* __restrict__ Btl,
    const float* __restrict__ bias,
    float* __restrict__ S, ushort* __restrict__ T, int M)
{
    const int tid = threadIdx.x;
    const int wave = tid >> 6;
    const int lane = tid & 63;
    const int lane16 = lane & 15;
    const int quad = lane >> 4;
    const int bm = blockIdx.x * 64 + wave * 16;

    const int row0 = bm + lane16;
    const bool ok0 = row0 < M;

    f32x4 acc[5] = {};

    #pragma unroll 2
    for (int c = 0; c < 4; ++c) {
        const int k0 = c * BKC + quad * 8;

        bf16x8 ah = {}, al = {};
        if (ok0) load_split_a(A + (long)row0 * KDIM + k0, ah, al);

        #pragma unroll
        for (int ct = 0; ct < 5; ++ct) {
            const long boff = (long)(16 * ct + lane16) * KDIM + k0;
            bf16x8 bh = *(const bf16x8*)(Bth + boff);
            bf16x8 bl = *(const bf16x8*)(Btl + boff);
            acc[ct] = __builtin_amdgcn_mfma_f32_16x16x32_bf16(ah, bh, acc[ct], 0, 0, 0);
            acc[ct] = __builtin_amdgcn_mfma_f32_16x16x32_bf16(ah, bl, acc[ct], 0, 0, 0);
            acc[ct] = __builtin_amdgcn_mfma_f32_16x16x32_bf16(al, bh, acc[ct], 0, 0, 0);
        }
    }

    #pragma unroll
    for (int ct = 0; ct < 5; ++ct) {
        int col = 16 * ct + lane16;
        bool toS = col < 40;
        float bv = toS ? bias[col] : 0.f;
        int tcol = toS ? col : col - 40;
        #pragma unroll
        for (int i = 0; i < 4; ++i) {
            int row = bm + quad * 4 + i;
            if (row < M) {
                if (toS) S[(long)row * 40 + tcol] = acc[ct][i] + bv;
                else     T[(long)row * 40 + tcol] = rne_bf16(acc[ct][i]);
            }
        }
    }
}

// ---------------- aggregation, wave-per-node, bf16 gather ----------------
// dout=128 (bf16 row = 256B): slot = lane>>4 (4 edges/instr, 16 lanes x 16B = 1 row),
// x2 unroll -> 8 edges in flight. Accumulate fp32.

template <int RELU>
__global__ __launch_bounds__(256) void agg128_kernel(
    const float* __restrict__ S, const ushort* __restrict__ T,
    const int* __restrict__ off, const int* __restrict__ ssrc,
    float* __restrict__ out, int nnodes)
{
    const int node = (blockIdx.x * 256 + threadIdx.x) >> 6;
    if (node >= nnodes) return;
    const int lane = threadIdx.x & 63;
    const int slot = lane >> 4;          // 0..3
    const int col8 = (lane & 15) * 8;    // 8 features per lane

    const int a = off[node];
    const int b = off[node + 1];

    f32x4 acc0a = {0,0,0,0}, acc0b = {0,0,0,0};
    f32x4 acc1a = {0,0,0,0}, acc1b = {0,0,0,0};

    int i = a;
    for (; i + 8 <= b; i += 8) {
        int s0 = ssrc[i + slot];
        int s1 = ssrc[i + 4 + slot];
        u16x8 v0 = *(const u16x8*)(T + (long)s0 * 128 + col8);
        u16x8 v1 = *(const u16x8*)(T + (long)s1 * 128 + col8);
        #pragma unroll
        for (int j = 0; j < 4; ++j) {
            acc0a[j] += bf16_to_f32(v0[j]);
            acc0b[j] += bf16_to_f32(v0[4 + j]);
            acc1a[j] += bf16_to_f32(v1[j]);
            acc1b[j] += bf16_to_f32(v1[4 + j]);
        }
    }
    for (; i < b; i += 4) {
        int e = i + slot;
        if (e < b) {
            int s = ssrc[e];
            u16x8 v = *(const u16x8*)(T + (long)s * 128 + col8);
            #pragma unroll
            for (int j = 0; j < 4; ++j) {
                acc0a[j] += bf16_to_f32(v[j]);
                acc0b[j] += bf16_to_f32(v[4 + j]);
            }
        }
    }
    f32x4 accA = acc0a + acc1a;
    f32x4 accB = acc0b + acc1b;

    // reduce across the 4 slots
    #pragma unroll
    for (int m = 16; m <= 32; m <<= 1) {
        #pragma unroll
        for (int j = 0; j < 4; ++j) {
            accA[j] += __shfl_xor((float)accA[j], m);
            accB[j] += __shfl_xor((float)accB[j], m);
        }
    }

    if (slot == 0) {
        int deg = b - a;
        float scale = (deg > 0) ? (1.0f / (float)deg) : 0.f;
        f32x4 sA = *(const f32x4*)(S + (long)node * 128 + col8);
        f32x4 sB = *(const f32x4*)(S + (long)node * 128 + col8 + 4);
        f32x4 rA = sA + accA * scale;
        f32x4 rB = sB + accB * scale;
        if (RELU) {
            #pragma unroll
            for (int j = 0; j < 4; ++j) {
                rA[j] = fmaxf(rA[j], 0.f);
                rB[j] = fmaxf(rB[j], 0.f);
            }
        }
        *(f32x4*)(out + (long)node * 128 + col8) = rA;
        *(f32x4*)(out + (long)node * 128 + col8 + 4) = rB;
    }
}

// dout=40 (bf16 row = 80B): 10 lanes/row (4 bf16 each), slot = lane/10 (6 edges/instr).
template <int RELU>
__global__ __launch_bounds__(256) void agg40_kernel(
    const float* __restrict__ S, const ushort* __restrict__ T,
    const int* __restrict__ off, const int* __restrict__ ssrc,
    float* __restrict__ out, int nnodes)
{
    const int node = (blockIdx.x * 256 + threadIdx.x) >> 6;
    if (node >= nnodes) return;
    const int lane = threadIdx.x & 63;
    const bool active = lane < 60;
    const int slot = active ? (lane / 10) : 5;   // 0..5
    const int fi = lane % 10;
    const int fo = fi * 4;

    const int a = off[node];
    const int b = off[node + 1];

    f32x4 acc0 = {0,0,0,0}, acc1 = {0,0,0,0};

    int i = a;
    for (; i + 12 <= b; i += 12) {
        int s0 = ssrc[i + slot];
        int s1 = ssrc[i + 6 + slot];
        u16x4 v0 = *(const u16x4*)(T + (long)s0 * 40 + fo);
        u16x4 v1 = *(const u16x4*)(T + (long)s1 * 40 + fo);
        if (active) {
            #pragma unroll
            for (int j = 0; j < 4; ++j) {
                acc0[j] += bf16_to_f32(v0[j]);
                acc1[j] += bf16_to_f32(v1[j]);
            }
        }
    }
    for (; i < b; i += 6) {
        int e = i + slot;
        if (active && e < b) {
            int s = ssrc[e];
            u16x4 v = *(const u16x4*)(T + (long)s * 40 + fo);
            #pragma unroll
            for (int j = 0; j < 4; ++j) acc0[j] += bf16_to_f32(v[j]);
        }
    }
    f32x4 acc = acc0 + acc1;

    f32x4 tot = acc;
    #pragma unroll
    for (int d = 10; d <= 50; d += 10) {
        int srcl = fi + d;
        #pragma unroll
        for (int j = 0; j < 4; ++j) tot[j] += __shfl((float)acc[j], srcl);
    }

    if (lane < 10) {
        int deg = b - a;
        float scale = (deg > 0) ? (1.0f / (float)deg) : 0.f;
        f32x4 s4 = *(const f32x4*)(S + (long)node * 40 + fo);
        f32x4 r = s4 + tot * scale;
        if (RELU) {
            #pragma unroll
            for (int j = 0; j < 4; ++j) r[j] = fmaxf(r[j], 0.f);
        }
        *(f32x4*)(out + (long)node * 40 + fo) = r;
    }
}

// ---------------- launch ----------------

extern "C" void kernel_launch(void* const* d_in, const int* in_sizes, int n_in,
                              void* d_out, int out_size, void* d_ws, size_t ws_size,
                              hipStream_t stream) {
    const float* feat = (const float*)d_in[0];
    const int*   src  = (const int*)d_in[1];
    const int*   dst  = (const int*)d_in[2];
    const float* ws0  = (const float*)d_in[3];
    const float* wn0  = (const float*)d_in[4];
    const float* b0   = (const float*)d_in[5];
    const float* ws1  = (const float*)d_in[6];
    const float* wn1  = (const float*)d_in[7];
    const float* b1   = (const float*)d_in[8];
    const float* ws2  = (const float*)d_in[9];
    const float* wn2  = (const float*)d_in[10];
    const float* b2   = (const float*)d_in[11];

    const int N = N_NODES;
    const int NE = N_EDGES;
    const int NB = (N + 255) / 256;  // 196

    char* ws = (char*)d_ws;
    int*    offsets = (int*)(ws + 0);
    int*    cursor  = (int*)(ws + 200704);
    int*    degi    = (int*)(ws + 401408);
    int*    bsum    = (int*)(ws + 601600);
    int*    bbase   = (int*)(ws + 602432);
    int*    ssrc    = (int*)(ws + 603648);
    ushort* Bth0 = (ushort*)(ws + 200704);   // overlap cursor/degi, written after CSR build
    ushort* Btl0 = (ushort*)(ws + 266240);
    ushort* Bth1 = (ushort*)(ws + 331776);
    ushort* Btl1 = (ushort*)(ws + 397312);
    ushort* Bth2 = (ushort*)(ws + 462848);
    ushort* Btl2 = (ushort*)(ws + 483328);
    float*  hbuf = (float*)(ws + 3003904);   // 25.6 MB fp32
    float*  sbuf = (float*)(ws + 28603904);  // 25.6 MB fp32
    ushort* tbuf = (ushort*)(ws + 54203904); // 12.8 MB bf16

    // ---- CSR build ----
    hipMemsetAsync(degi, 0, (size_t)N * sizeof(int), stream);
    count_deg_kernel<<<(NE + 255) / 256, 256, 0, stream>>>(dst, degi, NE);
    block_sums_kernel<<<NB, 256, 0, stream>>>(degi, bsum, N);
    scan_bsums_kernel<<<1, 256, 0, stream>>>(bsum, bbase, NB, offsets, N);
    scatter_offsets_kernel<<<NB, 256, 0, stream>>>(degi, bbase, offsets, cursor, N);
    fill_csr_kernel<<<(NE + 255) / 256, 256, 0, stream>>>(src, dst, cursor, ssrc, NE);

    // ---- weight pre-convert ----
    convert_w_kernel<<<256, 128, 0, stream>>>(ws0, wn0, 128, Bth0, Btl0);
    convert_w_kernel<<<256, 128, 0, stream>>>(ws1, wn1, 128, Bth1, Btl1);
    convert_w_kernel<<<80, 128, 0, stream>>>(ws2, wn2, 40, Bth2, Btl2);

    const int gw = (N + 31) / 32;        // 1563 wide-GEMM blocks (32 rows each)
    const int gn = (N + 63) / 64;        // 782 narrow-GEMM blocks (64 rows each)
    const int ga = (N + 3) / 4;          // 12500 agg blocks (4 waves/block)

    // ---- layer 0 ----
    gemm_mfma_wide<<<gw, 256, 0, stream>>>(feat, Bth0, Btl0, b0, sbuf, tbuf, N);
    agg128_kernel<1><<<ga, 256, 0, stream>>>(sbuf, tbuf, offsets, ssrc, hbuf, N);

    // ---- layer 1 ----
    gemm_mfma_wide<<<gw, 256, 0, stream>>>(hbuf, Bth1, Btl1, b1, sbuf, tbuf, N);
    agg128_kernel<1><<<ga, 256, 0, stream>>>(sbuf, tbuf, offsets, ssrc, hbuf, N);

    // ---- layer 2 ----
    gemm_mfma_narrow<<<gn, 256, 0, stream>>>(hbuf, Bth2, Btl2, b2, sbuf, tbuf, N);
    agg40_kernel<0><<<ga, 256, 0, stream>>>(sbuf, tbuf, offsets, ssrc, (float*)d_out, N);
}

// Round 2
// 340.276 us; speedup vs baseline: 1.0978x; 1.0978x over previous
//
#include <hip/hip_runtime.h>

#define N_NODES 50000
#define N_EDGES 600000

typedef short bf16x8 __attribute__((ext_vector_type(8)));
typedef float f32x4  __attribute__((ext_vector_type(4)));
typedef unsigned short u16x8 __attribute__((ext_vector_type(8)));
typedef unsigned short u16x4 __attribute__((ext_vector_type(4)));

// ---------------- bf16 helpers (RNE) ----------------
__device__ inline ushort rne_bf16(float a) {
    union { float f; unsigned u; } v; v.f = a;
    return (ushort)((v.u + 0x7FFFu + ((v.u >> 16) & 1u)) >> 16);
}
__device__ inline float bf16_to_f32(ushort h) {
    return __uint_as_float((unsigned)h << 16);
}
__device__ inline void split_bf16(float a, ushort& hi, ushort& lo) {
    hi = rne_bf16(a);
    float hv = bf16_to_f32(hi);
    lo = rne_bf16(a - hv);
}

// ---------------- CSR build ----------------

__global__ void count_deg_kernel(const int* __restrict__ dst, int* __restrict__ deg, int ne) {
    int e = blockIdx.x * blockDim.x + threadIdx.x;
    if (e < ne) atomicAdd(&deg[dst[e]], 1);
}

__global__ __launch_bounds__(256) void block_sums_kernel(const int* __restrict__ deg,
                                                         int* __restrict__ bsum, int n) {
    __shared__ int s[256];
    int t = threadIdx.x;
    int i = blockIdx.x * 256 + t;
    s[t] = (i < n) ? deg[i] : 0;
    __syncthreads();
    #pragma unroll
    for (int d = 128; d > 0; d >>= 1) {
        if (t < d) s[t] += s[t + d];
        __syncthreads();
    }
    if (t == 0) bsum[blockIdx.x] = s[0];
}

__global__ __launch_bounds__(256) void scan_bsums_kernel(const int* __restrict__ bsum,
                                                         int* __restrict__ base, int nb,
                                                         int* __restrict__ off, int n) {
    __shared__ int s[256];
    int t = threadIdx.x;
    int v = (t < nb) ? bsum[t] : 0;
    s[t] = v;
    __syncthreads();
    #pragma unroll
    for (int d = 1; d < 256; d <<= 1) {
        int x = (t >= d) ? s[t - d] : 0;
        __syncthreads();
        s[t] += x;
        __syncthreads();
    }
    if (t < nb) base[t] = s[t] - v;
    if (t == 255) off[n] = s[255];
}

__global__ __launch_bounds__(256) void scatter_offsets_kernel(const int* __restrict__ deg,
                                                              const int* __restrict__ base,
                                                              int* __restrict__ off,
                                                              int* __restrict__ cur, int n) {
    __shared__ int s[256];
    int t = threadIdx.x;
    int i = blockIdx.x * 256 + t;
    int v = (i < n) ? deg[i] : 0;
    s[t] = v;
    __syncthreads();
    #pragma unroll
    for (int d = 1; d < 256; d <<= 1) {
        int x = (t >= d) ? s[t - d] : 0;
        __syncthreads();
        s[t] += x;
        __syncthreads();
    }
    if (i < n) {
        int excl = s[t] - v + base[blockIdx.x];
        off[i] = excl;
        cur[i] = excl;
    }
}

__global__ void fill_csr_kernel(const int* __restrict__ src, const int* __restrict__ dst,
                                int* __restrict__ cur, int* __restrict__ ssrc, int ne) {
    int e = blockIdx.x * blockDim.x + threadIdx.x;
    if (e < ne) {
        int p = atomicAdd(&cur[dst[e]], 1);
        ssrc[p] = src[e];
    }
}

// ---------------- weight pre-convert ----------------
__global__ void convert_w_kernel(const float* __restrict__ Ws, const float* __restrict__ Wn,
                                 int dout, ushort* __restrict__ Bth, ushort* __restrict__ Btl) {
    int n = blockIdx.x;
    int k = threadIdx.x;
    float w = (n < dout) ? Ws[(long)k * dout + n] : Wn[(long)k * dout + (n - dout)];
    ushort hi, lo;
    split_bf16(w, hi, lo);
    Bth[n * 128 + k] = hi;
    Btl[n * 128 + k] = lo;
}

// ---------------- split-bf16 MFMA dual GEMM ----------------
// S = A@Ws + bias (fp32), T = A@Wn (stored bf16 for the cheap gather).
// Full-K (128) A-tile staged ONCE in LDS as hi/lo bf16 -> compute phase is
// barrier-free (192 MFMAs + L2-resident B loads, compiler hoists freely).
// MFMA operands are SWAPPED (weight as A-operand): lane then owns 4
// consecutive output COLUMNS of one row -> 16B/8B coalesced stores.
// Triple-product split keeps numerics identical: (Wh,Ah)+(Wl,Ah)+(Wh,Al)
// == (Ah,Wh)+(Ah,Wl)+(Al,Wh) with same accumulation order.

#define KDIM 128
#define APAD 136   // 128 + 8 ushorts pad (row stride 272B -> 2-way banks, free)

__device__ inline void stage_a_full(const float* __restrict__ A, int bm, int M, int tid,
                                    ushort* __restrict__ Ahi, ushort* __restrict__ Alo) {
    const int m  = tid >> 2;            // 0..63
    const int kq = (tid & 3) * 32;      // 0,32,64,96
    const int grow = bm + m;
    #pragma unroll
    for (int g = 0; g < 4; ++g) {
        float f[8];
        if (grow < M) {
            const float* ap = A + (long)grow * KDIM + kq + g * 8;
            float4 a0 = *(const float4*)ap;
            float4 a1 = *(const float4*)(ap + 4);
            f[0] = a0.x; f[1] = a0.y; f[2] = a0.z; f[3] = a0.w;
            f[4] = a1.x; f[5] = a1.y; f[6] = a1.z; f[7] = a1.w;
        } else {
            #pragma unroll
            for (int i = 0; i < 8; ++i) f[i] = 0.f;
        }
        ushort h[8], l[8];
        #pragma unroll
        for (int i = 0; i < 8; ++i) split_bf16(f[i], h[i], l[i]);
        uint4 hw, lw;
        hw.x = (unsigned)h[0] | ((unsigned)h[1] << 16);
        hw.y = (unsigned)h[2] | ((unsigned)h[3] << 16);
        hw.z = (unsigned)h[4] | ((unsigned)h[5] << 16);
        hw.w = (unsigned)h[6] | ((unsigned)h[7] << 16);
        lw.x = (unsigned)l[0] | ((unsigned)l[1] << 16);
        lw.y = (unsigned)l[2] | ((unsigned)l[3] << 16);
        lw.z = (unsigned)l[4] | ((unsigned)l[5] << 16);
        lw.w = (unsigned)l[6] | ((unsigned)l[7] << 16);
        *(uint4*)&Ahi[m * APAD + kq + g * 8] = hw;
        *(uint4*)&Alo[m * APAD + kq + g * 8] = lw;
    }
}

// Wide: dout=128 dual (256 cols). Block = 64 rows x 256 cols, wave = 64 rows x 64 cols.
__global__ __launch_bounds__(256) void gemm_mfma_wide(
    const float* __restrict__ A,
    const ushort* __restrict__ Bth, const ushort* __restrict__ Btl,
    const float* __restrict__ bias,
    float* __restrict__ S, ushort* __restrict__ T, int M)
{
    __shared__ ushort Ahi[64 * APAD];
    __shared__ ushort Alo[64 * APAD];

    const int tid = threadIdx.x;
    const int wave = tid >> 6;
    const int lane = tid & 63;
    const int lane16 = lane & 15;
    const int quad = lane >> 4;
    const int bm = blockIdx.x * 64;
    const int colbase = wave * 64;

    stage_a_full(A, bm, M, tid, Ahi, Alo);
    __syncthreads();

    f32x4 acc[4][4] = {};

    #pragma unroll
    for (int c = 0; c < 4; ++c) {
        const int k0 = c * 32 + quad * 8;
        bf16x8 ah[4], al[4];
        #pragma unroll
        for (int r = 0; r < 4; ++r) {
            int off = (16 * r + lane16) * APAD + k0;
            ah[r] = *(const bf16x8*)&Ahi[off];
            al[r] = *(const bf16x8*)&Alo[off];
        }
        #pragma unroll
        for (int ct = 0; ct < 4; ++ct) {
            const long boff = (long)(colbase + 16 * ct + lane16) * KDIM + k0;
            bf16x8 bh = *(const bf16x8*)(Bth + boff);
            bf16x8 bl = *(const bf16x8*)(Btl + boff);
            #pragma unroll
            for (int r = 0; r < 4; ++r) {
                acc[r][ct] = __builtin_amdgcn_mfma_f32_16x16x32_bf16(bh, ah[r], acc[r][ct], 0, 0, 0);
                acc[r][ct] = __builtin_amdgcn_mfma_f32_16x16x32_bf16(bl, ah[r], acc[r][ct], 0, 0, 0);
                acc[r][ct] = __builtin_amdgcn_mfma_f32_16x16x32_bf16(bh, al[r], acc[r][ct], 0, 0, 0);
            }
        }
    }

    // Swapped C/D mapping: acc[r][ct][i] = C[bm+16r+lane16][colbase+16ct+quad*4+i]
    #pragma unroll
    for (int ct = 0; ct < 4; ++ct) {
        const int col0 = colbase + 16 * ct + quad * 4;
        const bool toS = col0 < 128;
        f32x4 bv = {0,0,0,0};
        if (toS) bv = *(const f32x4*)(bias + col0);
        #pragma unroll
        for (int r = 0; r < 4; ++r) {
            const int row = bm + 16 * r + lane16;
            if (row < M) {
                if (toS) {
                    *(f32x4*)(S + (long)row * 128 + col0) = acc[r][ct] + bv;
                } else {
                    u16x4 t4;
                    #pragma unroll
                    for (int i = 0; i < 4; ++i) t4[i] = rne_bf16(acc[r][ct][i]);
                    *(u16x4*)(T + (long)row * 128 + (col0 - 128)) = t4;
                }
            }
        }
    }
}

// Narrow: dout=40 dual (80 cols). Block = 64 rows, wave = 16 rows x 80 cols (5 ct).
__global__ __launch_bounds__(256) void gemm_mfma_narrow(
    const float* __restrict__ A,
    const ushort* __restrict__ Bth, const ushort* __restrict__ Btl,
    const float* __restrict__ bias,
    float* __restrict__ S, ushort* __restrict__ T, int M)
{
    __shared__ ushort Ahi[64 * APAD];
    __shared__ ushort Alo[64 * APAD];

    const int tid = threadIdx.x;
    const int wave = tid >> 6;
    const int lane = tid & 63;
    const int lane16 = lane & 15;
    const int quad = lane >> 4;
    const int bm = blockIdx.x * 64;

    stage_a_full(A, bm, M, tid, Ahi, Alo);
    __syncthreads();

    f32x4 acc[5] = {};

    #pragma unroll
    for (int c = 0; c < 4; ++c) {
        const int k0 = c * 32 + quad * 8;
        const int off = (16 * wave + lane16) * APAD + k0;
        bf16x8 ah = *(const bf16x8*)&Ahi[off];
        bf16x8 al = *(const bf16x8*)&Alo[off];
        #pragma unroll
        for (int ct = 0; ct < 5; ++ct) {
            const long boff = (long)(16 * ct + lane16) * KDIM + k0;
            bf16x8 bh = *(const bf16x8*)(Bth + boff);
            bf16x8 bl = *(const bf16x8*)(Btl + boff);
            acc[ct] = __builtin_amdgcn_mfma_f32_16x16x32_bf16(bh, ah, acc[ct], 0, 0, 0);
            acc[ct] = __builtin_amdgcn_mfma_f32_16x16x32_bf16(bl, ah, acc[ct], 0, 0, 0);
            acc[ct] = __builtin_amdgcn_mfma_f32_16x16x32_bf16(bh, al, acc[ct], 0, 0, 0);
        }
    }

    #pragma unroll
    for (int ct = 0; ct < 5; ++ct) {
        const int col0 = 16 * ct + quad * 4;
        const bool toS = col0 < 40;
        const int row = bm + 16 * wave + lane16;
        if (row < M) {
            if (toS) {
                f32x4 bv = *(const f32x4*)(bias + col0);
                *(f32x4*)(S + (long)row * 40 + col0) = acc[ct] + bv;
            } else {
                u16x4 t4;
                #pragma unroll
                for (int i = 0; i < 4; ++i) t4[i] = rne_bf16(acc[ct][i]);
                *(u16x4*)(T + (long)row * 40 + (col0 - 40)) = t4;
            }
        }
    }
}

// ---------------- aggregation, wave-per-node, bf16 gather ----------------

template <int RELU>
__global__ __launch_bounds__(256) void agg128_kernel(
    const float* __restrict__ S, const ushort* __restrict__ T,
    const int* __restrict__ off, const int* __restrict__ ssrc,
    float* __restrict__ out, int nnodes)
{
    const int node = (blockIdx.x * 256 + threadIdx.x) >> 6;
    if (node >= nnodes) return;
    const int lane = threadIdx.x & 63;
    const int slot = lane >> 4;          // 0..3
    const int col8 = (lane & 15) * 8;    // 8 features per lane

    const int a = off[node];
    const int b = off[node + 1];

    f32x4 acc0a = {0,0,0,0}, acc0b = {0,0,0,0};
    f32x4 acc1a = {0,0,0,0}, acc1b = {0,0,0,0};

    int i = a;
    for (; i + 8 <= b; i += 8) {
        int s0 = ssrc[i + slot];
        int s1 = ssrc[i + 4 + slot];
        u16x8 v0 = *(const u16x8*)(T + (long)s0 * 128 + col8);
        u16x8 v1 = *(const u16x8*)(T + (long)s1 * 128 + col8);
        #pragma unroll
        for (int j = 0; j < 4; ++j) {
            acc0a[j] += bf16_to_f32(v0[j]);
            acc0b[j] += bf16_to_f32(v0[4 + j]);
            acc1a[j] += bf16_to_f32(v1[j]);
            acc1b[j] += bf16_to_f32(v1[4 + j]);
        }
    }
    for (; i < b; i += 4) {
        int e = i + slot;
        if (e < b) {
            int s = ssrc[e];
            u16x8 v = *(const u16x8*)(T + (long)s * 128 + col8);
            #pragma unroll
            for (int j = 0; j < 4; ++j) {
                acc0a[j] += bf16_to_f32(v[j]);
                acc0b[j] += bf16_to_f32(v[4 + j]);
            }
        }
    }
    f32x4 accA = acc0a + acc1a;
    f32x4 accB = acc0b + acc1b;

    // reduce across the 4 slots
    #pragma unroll
    for (int m = 16; m <= 32; m <<= 1) {
        #pragma unroll
        for (int j = 0; j < 4; ++j) {
            accA[j] += __shfl_xor((float)accA[j], m);
            accB[j] += __shfl_xor((float)accB[j], m);
        }
    }

    if (slot == 0) {
        int deg = b - a;
        float scale = (deg > 0) ? (1.0f / (float)deg) : 0.f;
        f32x4 sA = *(const f32x4*)(S + (long)node * 128 + col8);
        f32x4 sB = *(const f32x4*)(S + (long)node * 128 + col8 + 4);
        f32x4 rA = sA + accA * scale;
        f32x4 rB = sB + accB * scale;
        if (RELU) {
            #pragma unroll
            for (int j = 0; j < 4; ++j) {
                rA[j] = fmaxf(rA[j], 0.f);
                rB[j] = fmaxf(rB[j], 0.f);
            }
        }
        *(f32x4*)(out + (long)node * 128 + col8) = rA;
        *(f32x4*)(out + (long)node * 128 + col8 + 4) = rB;
    }
}

template <int RELU>
__global__ __launch_bounds__(256) void agg40_kernel(
    const float* __restrict__ S, const ushort* __restrict__ T,
    const int* __restrict__ off, const int* __restrict__ ssrc,
    float* __restrict__ out, int nnodes)
{
    const int node = (blockIdx.x * 256 + threadIdx.x) >> 6;
    if (node >= nnodes) return;
    const int lane = threadIdx.x & 63;
    const bool active = lane < 60;
    const int slot = active ? (lane / 10) : 5;   // 0..5
    const int fi = lane % 10;
    const int fo = fi * 4;

    const int a = off[node];
    const int b = off[node + 1];

    f32x4 acc0 = {0,0,0,0}, acc1 = {0,0,0,0};

    int i = a;
    for (; i + 12 <= b; i += 12) {
        int s0 = ssrc[i + slot];
        int s1 = ssrc[i + 6 + slot];
        u16x4 v0 = *(const u16x4*)(T + (long)s0 * 40 + fo);
        u16x4 v1 = *(const u16x4*)(T + (long)s1 * 40 + fo);
        if (active) {
            #pragma unroll
            for (int j = 0; j < 4; ++j) {
                acc0[j] += bf16_to_f32(v0[j]);
                acc1[j] += bf16_to_f32(v1[j]);
            }
        }
    }
    for (; i < b; i += 6) {
        int e = i + slot;
        if (active && e < b) {
            int s = ssrc[e];
            u16x4 v = *(const u16x4*)(T + (long)s * 40 + fo);
            #pragma unroll
            for (int j = 0; j < 4; ++j) acc0[j] += bf16_to_f32(v[j]);
        }
    }
    f32x4 acc = acc0 + acc1;

    f32x4 tot = acc;
    #pragma unroll
    for (int d = 10; d <= 50; d += 10) {
        int srcl = fi + d;
        #pragma unroll
        for (int j = 0; j < 4; ++j) tot[j] += __shfl((float)acc[j], srcl);
    }

    if (lane < 10) {
        int deg = b - a;
        float scale = (deg > 0) ? (1.0f / (float)deg) : 0.f;
        f32x4 s4 = *(const f32x4*)(S + (long)node * 40 + fo);
        f32x4 r = s4 + tot * scale;
        if (RELU) {
            #pragma unroll
            for (int j = 0; j < 4; ++j) r[j] = fmaxf(r[j], 0.f);
        }
        *(f32x4*)(out + (long)node * 40 + fo) = r;
    }
}

// ---------------- launch ----------------

extern "C" void kernel_launch(void* const* d_in, const int* in_sizes, int n_in,
                              void* d_out, int out_size, void* d_ws, size_t ws_size,
                              hipStream_t stream) {
    const float* feat = (const float*)d_in[0];
    const int*   src  = (const int*)d_in[1];
    const int*   dst  = (const int*)d_in[2];
    const float* ws0  = (const float*)d_in[3];
    const float* wn0  = (const float*)d_in[4];
    const float* b0   = (const float*)d_in[5];
    const float* ws1  = (const float*)d_in[6];
    const float* wn1  = (const float*)d_in[7];
    const float* b1   = (const float*)d_in[8];
    const float* ws2  = (const float*)d_in[9];
    const float* wn2  = (const float*)d_in[10];
    const float* b2   = (const float*)d_in[11];

    const int N = N_NODES;
    const int NE = N_EDGES;
    const int NB = (N + 255) / 256;  // 196

    char* ws = (char*)d_ws;
    int*    offsets = (int*)(ws + 0);
    int*    cursor  = (int*)(ws + 200704);
    int*    degi    = (int*)(ws + 401408);
    int*    bsum    = (int*)(ws + 601600);
    int*    bbase   = (int*)(ws + 602432);
    int*    ssrc    = (int*)(ws + 603648);
    ushort* Bth0 = (ushort*)(ws + 200704);   // overlap cursor/degi, written after CSR build
    ushort* Btl0 = (ushort*)(ws + 266240);
    ushort* Bth1 = (ushort*)(ws + 331776);
    ushort* Btl1 = (ushort*)(ws + 397312);
    ushort* Bth2 = (ushort*)(ws + 462848);
    ushort* Btl2 = (ushort*)(ws + 483328);
    float*  hbuf = (float*)(ws + 3003904);   // 25.6 MB fp32
    float*  sbuf = (float*)(ws + 28603904);  // 25.6 MB fp32
    ushort* tbuf = (ushort*)(ws + 54203904); // 12.8 MB bf16

    // ---- CSR build ----
    hipMemsetAsync(degi, 0, (size_t)N * sizeof(int), stream);
    count_deg_kernel<<<(NE + 255) / 256, 256, 0, stream>>>(dst, degi, NE);
    block_sums_kernel<<<NB, 256, 0, stream>>>(degi, bsum, N);
    scan_bsums_kernel<<<1, 256, 0, stream>>>(bsum, bbase, NB, offsets, N);
    scatter_offsets_kernel<<<NB, 256, 0, stream>>>(degi, bbase, offsets, cursor, N);
    fill_csr_kernel<<<(NE + 255) / 256, 256, 0, stream>>>(src, dst, cursor, ssrc, NE);

    // ---- weight pre-convert ----
    convert_w_kernel<<<256, 128, 0, stream>>>(ws0, wn0, 128, Bth0, Btl0);
    convert_w_kernel<<<256, 128, 0, stream>>>(ws1, wn1, 128, Bth1, Btl1);
    convert_w_kernel<<<80, 128, 0, stream>>>(ws2, wn2, 40, Bth2, Btl2);

    const int gx = (N + 63) / 64;        // 782 GEMM blocks (64 rows each)
    const int ga = (N + 3) / 4;          // 12500 agg blocks (4 waves/block)

    // ---- layer 0 ----
    gemm_mfma_wide<<<gx, 256, 0, stream>>>(feat, Bth0, Btl0, b0, sbuf, tbuf, N);
    agg128_kernel<1><<<ga, 256, 0, stream>>>(sbuf, tbuf, offsets, ssrc, hbuf, N);

    // ---- layer 1 ----
    gemm_mfma_wide<<<gx, 256, 0, stream>>>(hbuf, Bth1, Btl1, b1, sbuf, tbuf, N);
    agg128_kernel<1><<<ga, 256, 0, stream>>>(sbuf, tbuf, offsets, ssrc, hbuf, N);

    // ---- layer 2 ----
    gemm_mfma_narrow<<<gx, 256, 0, stream>>>(hbuf, Bth2, Btl2, b2, sbuf, tbuf, N);
    agg40_kernel<0><<<ga, 256, 0, stream>>>(sbuf, tbuf, offsets, ssrc, (float*)d_out, N);
}

// Round 3
// 330.363 us; speedup vs baseline: 1.1308x; 1.0300x over previous
//
#include <hip/hip_runtime.h>

#define N_NODES 50000
#define N_EDGES 600000

typedef short bf16x8 __attribute__((ext_vector_type(8)));
typedef float f32x4  __attribute__((ext_vector_type(4)));
typedef unsigned short u16x8 __attribute__((ext_vector_type(8)));
typedef unsigned short u16x4 __attribute__((ext_vector_type(4)));

// ---------------- bf16 helpers (RNE) ----------------
__device__ inline ushort rne_bf16(float a) {
    union { float f; unsigned u; } v; v.f = a;
    return (ushort)((v.u + 0x7FFFu + ((v.u >> 16) & 1u)) >> 16);
}
__device__ inline float bf16_to_f32(ushort h) {
    return __uint_as_float((unsigned)h << 16);
}
__device__ inline void split_bf16(float a, ushort& hi, ushort& lo) {
    hi = rne_bf16(a);
    float hv = bf16_to_f32(hi);
    lo = rne_bf16(a - hv);
}

// ---------------- CSR build ----------------

__global__ void count_deg_kernel(const int* __restrict__ dst, int* __restrict__ deg, int ne) {
    int e = blockIdx.x * blockDim.x + threadIdx.x;
    if (e < ne) atomicAdd(&deg[dst[e]], 1);
}

__global__ __launch_bounds__(256) void block_sums_kernel(const int* __restrict__ deg,
                                                         int* __restrict__ bsum, int n) {
    __shared__ int s[256];
    int t = threadIdx.x;
    int i = blockIdx.x * 256 + t;
    s[t] = (i < n) ? deg[i] : 0;
    __syncthreads();
    #pragma unroll
    for (int d = 128; d > 0; d >>= 1) {
        if (t < d) s[t] += s[t + d];
        __syncthreads();
    }
    if (t == 0) bsum[blockIdx.x] = s[0];
}

// Fused: re-scan the 196 block sums per block (cheap), then per-block scan of deg.
__global__ __launch_bounds__(256) void scatter_fused_kernel(const int* __restrict__ deg,
                                                            const int* __restrict__ bsum,
                                                            int* __restrict__ off,
                                                            int* __restrict__ cur,
                                                            int n, int nb) {
    __shared__ int s[256];
    int t = threadIdx.x;

    // scan of block sums
    int bv = (t < nb) ? bsum[t] : 0;
    s[t] = bv;
    __syncthreads();
    #pragma unroll
    for (int d = 1; d < 256; d <<= 1) {
        int x = (t >= d) ? s[t - d] : 0;
        __syncthreads();
        s[t] += x;
        __syncthreads();
    }
    int base = (blockIdx.x > 0) ? s[blockIdx.x - 1] : 0;   // exclusive base for this block
    if (blockIdx.x == 0 && t == 0) off[n] = s[255];        // total edges
    __syncthreads();

    // per-block scan of deg
    int i = blockIdx.x * 256 + t;
    int v = (i < n) ? deg[i] : 0;
    s[t] = v;
    __syncthreads();
    #pragma unroll
    for (int d = 1; d < 256; d <<= 1) {
        int x = (t >= d) ? s[t - d] : 0;
        __syncthreads();
        s[t] += x;
        __syncthreads();
    }
    if (i < n) {
        int excl = s[t] - v + base;
        off[i] = excl;
        cur[i] = excl;
    }
}

__global__ void fill_csr_kernel(const int* __restrict__ src, const int* __restrict__ dst,
                                int* __restrict__ cur, int* __restrict__ ssrc, int ne) {
    int e = blockIdx.x * blockDim.x + threadIdx.x;
    if (e < ne) {
        int p = atomicAdd(&cur[dst[e]], 1);
        ssrc[p] = src[e];
    }
}

// ---------------- weight pre-convert (all 3 layers, one dispatch) ----------------
__global__ void convert_all_w(const float* __restrict__ ws0, const float* __restrict__ wn0,
                              const float* __restrict__ ws1, const float* __restrict__ wn1,
                              const float* __restrict__ ws2, const float* __restrict__ wn2,
                              ushort* __restrict__ Bth0, ushort* __restrict__ Btl0,
                              ushort* __restrict__ Bth1, ushort* __restrict__ Btl1,
                              ushort* __restrict__ Bth2, ushort* __restrict__ Btl2) {
    int b = blockIdx.x;
    int k = threadIdx.x;
    const float *Ws, *Wn;
    ushort *H, *L;
    int dout, n;
    if (b < 256)      { n = b;       dout = 128; Ws = ws0; Wn = wn0; H = Bth0; L = Btl0; }
    else if (b < 512) { n = b - 256; dout = 128; Ws = ws1; Wn = wn1; H = Bth1; L = Btl1; }
    else              { n = b - 512; dout = 40;  Ws = ws2; Wn = wn2; H = Bth2; L = Btl2; }
    float w = (n < dout) ? Ws[(long)k * dout + n] : Wn[(long)k * dout + (n - dout)];
    ushort hi, lo;
    split_bf16(w, hi, lo);
    H[n * 128 + k] = hi;
    L[n * 128 + k] = lo;
}

// ---------------- split-bf16 MFMA dual GEMM ----------------
// Full-K (128) A-tile staged ONCE in LDS as hi/lo bf16. B loads register-
// prefetched 3 iterations ahead (rolling 4-slot buffer) to hide L2/L3 latency
// (VGPR_Count=80 in the previous version left no room for the compiler to
// hoist them; __launch_bounds__(256,3) raises the cap to ~170).
// MFMA operands SWAPPED (weight as A-operand) -> coalesced 16B/8B stores.

#define KDIM 128
#define APAD 136   // 128 + 8 ushorts pad

__device__ inline void stage_a_full(const float* __restrict__ A, int bm, int M, int tid,
                                    ushort* __restrict__ Ahi, ushort* __restrict__ Alo) {
    const int m  = tid >> 2;            // 0..63
    const int kq = (tid & 3) * 32;      // 0,32,64,96
    const int grow = bm + m;
    #pragma unroll
    for (int g = 0; g < 4; ++g) {
        float f[8];
        if (grow < M) {
            const float* ap = A + (long)grow * KDIM + kq + g * 8;
            float4 a0 = *(const float4*)ap;
            float4 a1 = *(const float4*)(ap + 4);
            f[0] = a0.x; f[1] = a0.y; f[2] = a0.z; f[3] = a0.w;
            f[4] = a1.x; f[5] = a1.y; f[6] = a1.z; f[7] = a1.w;
        } else {
            #pragma unroll
            for (int i = 0; i < 8; ++i) f[i] = 0.f;
        }
        ushort h[8], l[8];
        #pragma unroll
        for (int i = 0; i < 8; ++i) split_bf16(f[i], h[i], l[i]);
        uint4 hw, lw;
        hw.x = (unsigned)h[0] | ((unsigned)h[1] << 16);
        hw.y = (unsigned)h[2] | ((unsigned)h[3] << 16);
        hw.z = (unsigned)h[4] | ((unsigned)h[5] << 16);
        hw.w = (unsigned)h[6] | ((unsigned)h[7] << 16);
        lw.x = (unsigned)l[0] | ((unsigned)l[1] << 16);
        lw.y = (unsigned)l[2] | ((unsigned)l[3] << 16);
        lw.z = (unsigned)l[4] | ((unsigned)l[5] << 16);
        lw.w = (unsigned)l[6] | ((unsigned)l[7] << 16);
        *(uint4*)&Ahi[m * APAD + kq + g * 8] = hw;
        *(uint4*)&Alo[m * APAD + kq + g * 8] = lw;
    }
}

// Wide: dout=128 dual (256 cols). Block = 64 rows x 256 cols, wave = 64 rows x 64 cols.
__global__ __launch_bounds__(256, 3) void gemm_mfma_wide(
    const float* __restrict__ A,
    const ushort* __restrict__ Bth, const ushort* __restrict__ Btl,
    const float* __restrict__ bias,
    float* __restrict__ S, ushort* __restrict__ T, int M)
{
    __shared__ ushort Ahi[64 * APAD];
    __shared__ ushort Alo[64 * APAD];

    const int tid = threadIdx.x;
    const int wave = tid >> 6;
    const int lane = tid & 63;
    const int lane16 = lane & 15;
    const int quad = lane >> 4;
    const int bm = blockIdx.x * 64;
    const int colbase = wave * 64;

    stage_a_full(A, bm, M, tid, Ahi, Alo);
    __syncthreads();

    // per-lane B base; iteration it = c*4+ct reads offset ct*16*KDIM + c*32
    const ushort* Bh0 = Bth + (long)(colbase + lane16) * KDIM + quad * 8;
    const ushort* Bl0 = Btl + (long)(colbase + lane16) * KDIM + quad * 8;

    f32x4 acc[4][4] = {};
    bf16x8 bhb[4], blb[4];

    // prologue: issue B loads for it = 0,1,2
    #pragma unroll
    for (int p = 0; p < 3; ++p) {
        const int pc = p >> 2, pct = p & 3;
        bhb[p] = *(const bf16x8*)(Bh0 + pct * 16 * KDIM + pc * 32);
        blb[p] = *(const bf16x8*)(Bl0 + pct * 16 * KDIM + pc * 32);
    }

    bf16x8 ah[4], al[4];
    #pragma unroll
    for (int it = 0; it < 16; ++it) {
        const int c = it >> 2, ct = it & 3;
        if ((it & 3) == 0) {
            const int k0 = c * 32 + quad * 8;
            #pragma unroll
            for (int r = 0; r < 4; ++r) {
                int off = (16 * r + lane16) * APAD + k0;
                ah[r] = *(const bf16x8*)&Ahi[off];
                al[r] = *(const bf16x8*)&Alo[off];
            }
        }
        const int nx = it + 3;
        if (nx < 16) {
            const int nc = nx >> 2, nct = nx & 3;
            bhb[nx & 3] = *(const bf16x8*)(Bh0 + nct * 16 * KDIM + nc * 32);
            blb[nx & 3] = *(const bf16x8*)(Bl0 + nct * 16 * KDIM + nc * 32);
        }
        const bf16x8 bh = bhb[it & 3];
        const bf16x8 bl = blb[it & 3];
        #pragma unroll
        for (int r = 0; r < 4; ++r) {
            acc[r][ct] = __builtin_amdgcn_mfma_f32_16x16x32_bf16(bh, ah[r], acc[r][ct], 0, 0, 0);
            acc[r][ct] = __builtin_amdgcn_mfma_f32_16x16x32_bf16(bl, ah[r], acc[r][ct], 0, 0, 0);
            acc[r][ct] = __builtin_amdgcn_mfma_f32_16x16x32_bf16(bh, al[r], acc[r][ct], 0, 0, 0);
        }
    }

    // Swapped C/D mapping: acc[r][ct][i] = C[bm+16r+lane16][colbase+16ct+quad*4+i]
    #pragma unroll
    for (int ct = 0; ct < 4; ++ct) {
        const int col0 = colbase + 16 * ct + quad * 4;
        const bool toS = col0 < 128;
        f32x4 bv = {0,0,0,0};
        if (toS) bv = *(const f32x4*)(bias + col0);
        #pragma unroll
        for (int r = 0; r < 4; ++r) {
            const int row = bm + 16 * r + lane16;
            if (row < M) {
                if (toS) {
                    *(f32x4*)(S + (long)row * 128 + col0) = acc[r][ct] + bv;
                } else {
                    u16x4 t4;
                    #pragma unroll
                    for (int i = 0; i < 4; ++i) t4[i] = rne_bf16(acc[r][ct][i]);
                    *(u16x4*)(T + (long)row * 128 + (col0 - 128)) = t4;
                }
            }
        }
    }
}

// Narrow: dout=40 dual (80 cols). Block = 64 rows, wave = 16 rows x 80 cols (5 ct).
__global__ __launch_bounds__(256, 3) void gemm_mfma_narrow(
    const float* __restrict__ A,
    const ushort* __restrict__ Bth, const ushort* __restrict__ Btl,
    const float* __restrict__ bias,
    float* __restrict__ S, ushort* __restrict__ T, int M)
{
    __shared__ ushort Ahi[64 * APAD];
    __shared__ ushort Alo[64 * APAD];

    const int tid = threadIdx.x;
    const int wave = tid >> 6;
    const int lane = tid & 63;
    const int lane16 = lane & 15;
    const int quad = lane >> 4;
    const int bm = blockIdx.x * 64;

    stage_a_full(A, bm, M, tid, Ahi, Alo);
    __syncthreads();

    const ushort* Bh0 = Bth + (long)lane16 * KDIM + quad * 8;
    const ushort* Bl0 = Btl + (long)lane16 * KDIM + quad * 8;

    f32x4 acc[5] = {};
    bf16x8 bhb[4], blb[4];

    // it = c*5+ct, c=it/5, ct=it%5 (20 iterations)
    #pragma unroll
    for (int p = 0; p < 3; ++p) {
        const int pc = p / 5, pct = p % 5;
        bhb[p] = *(const bf16x8*)(Bh0 + pct * 16 * KDIM + pc * 32);
        blb[p] = *(const bf16x8*)(Bl0 + pct * 16 * KDIM + pc * 32);
    }

    bf16x8 ah = {}, al = {};
    #pragma unroll
    for (int it = 0; it < 20; ++it) {
        const int c = it / 5, ct = it % 5;
        if (ct == 0) {
            const int off = (16 * wave + lane16) * APAD + c * 32 + quad * 8;
            ah = *(const bf16x8*)&Ahi[off];
            al = *(const bf16x8*)&Alo[off];
        }
        const int nx = it + 3;
        if (nx < 20) {
            const int nc = nx / 5, nct = nx % 5;
            bhb[nx & 3] = *(const bf16x8*)(Bh0 + nct * 16 * KDIM + nc * 32);
            blb[nx & 3] = *(const bf16x8*)(Bl0 + nct * 16 * KDIM + nc * 32);
        }
        const bf16x8 bh = bhb[it & 3];
        const bf16x8 bl = blb[it & 3];
        acc[ct] = __builtin_amdgcn_mfma_f32_16x16x32_bf16(bh, ah, acc[ct], 0, 0, 0);
        acc[ct] = __builtin_amdgcn_mfma_f32_16x16x32_bf16(bl, ah, acc[ct], 0, 0, 0);
        acc[ct] = __builtin_amdgcn_mfma_f32_16x16x32_bf16(bh, al, acc[ct], 0, 0, 0);
    }

    #pragma unroll
    for (int ct = 0; ct < 5; ++ct) {
        const int col0 = 16 * ct + quad * 4;
        const bool toS = col0 < 40;
        const int row = bm + 16 * wave + lane16;
        if (row < M) {
            if (toS) {
                f32x4 bv = *(const f32x4*)(bias + col0);
                *(f32x4*)(S + (long)row * 40 + col0) = acc[ct] + bv;
            } else {
                u16x4 t4;
                #pragma unroll
                for (int i = 0; i < 4; ++i) t4[i] = rne_bf16(acc[ct][i]);
                *(u16x4*)(T + (long)row * 40 + (col0 - 40)) = t4;
            }
        }
    }
}

// ---------------- aggregation, wave-per-node, bf16 gather ----------------

template <int RELU>
__global__ __launch_bounds__(256) void agg128_kernel(
    const float* __restrict__ S, const ushort* __restrict__ T,
    const int* __restrict__ off, const int* __restrict__ ssrc,
    float* __restrict__ out, int nnodes)
{
    const int node = (blockIdx.x * 256 + threadIdx.x) >> 6;
    if (node >= nnodes) return;
    const int lane = threadIdx.x & 63;
    const int slot = lane >> 4;          // 0..3
    const int col8 = (lane & 15) * 8;    // 8 features per lane

    const int a = off[node];
    const int b = off[node + 1];

    f32x4 acc0a = {0,0,0,0}, acc0b = {0,0,0,0};
    f32x4 acc1a = {0,0,0,0}, acc1b = {0,0,0,0};

    int i = a;
    for (; i + 8 <= b; i += 8) {
        int s0 = ssrc[i + slot];
        int s1 = ssrc[i + 4 + slot];
        u16x8 v0 = *(const u16x8*)(T + (long)s0 * 128 + col8);
        u16x8 v1 = *(const u16x8*)(T + (long)s1 * 128 + col8);
        #pragma unroll
        for (int j = 0; j < 4; ++j) {
            acc0a[j] += bf16_to_f32(v0[j]);
            acc0b[j] += bf16_to_f32(v0[4 + j]);
            acc1a[j] += bf16_to_f32(v1[j]);
            acc1b[j] += bf16_to_f32(v1[4 + j]);
        }
    }
    for (; i < b; i += 4) {
        int e = i + slot;
        if (e < b) {
            int s = ssrc[e];
            u16x8 v = *(const u16x8*)(T + (long)s * 128 + col8);
            #pragma unroll
            for (int j = 0; j < 4; ++j) {
                acc0a[j] += bf16_to_f32(v[j]);
                acc0b[j] += bf16_to_f32(v[4 + j]);
            }
        }
    }
    f32x4 accA = acc0a + acc1a;
    f32x4 accB = acc0b + acc1b;

    // reduce across the 4 slots
    #pragma unroll
    for (int m = 16; m <= 32; m <<= 1) {
        #pragma unroll
        for (int j = 0; j < 4; ++j) {
            accA[j] += __shfl_xor((float)accA[j], m);
            accB[j] += __shfl_xor((float)accB[j], m);
        }
    }

    if (slot == 0) {
        int deg = b - a;
        float scale = (deg > 0) ? (1.0f / (float)deg) : 0.f;
        f32x4 sA = *(const f32x4*)(S + (long)node * 128 + col8);
        f32x4 sB = *(const f32x4*)(S + (long)node * 128 + col8 + 4);
        f32x4 rA = sA + accA * scale;
        f32x4 rB = sB + accB * scale;
        if (RELU) {
            #pragma unroll
            for (int j = 0; j < 4; ++j) {
                rA[j] = fmaxf(rA[j], 0.f);
                rB[j] = fmaxf(rB[j], 0.f);
            }
        }
        *(f32x4*)(out + (long)node * 128 + col8) = rA;
        *(f32x4*)(out + (long)node * 128 + col8 + 4) = rB;
    }
}

template <int RELU>
__global__ __launch_bounds__(256) void agg40_kernel(
    const float* __restrict__ S, const ushort* __restrict__ T,
    const int* __restrict__ off, const int* __restrict__ ssrc,
    float* __restrict__ out, int nnodes)
{
    const int node = (blockIdx.x * 256 + threadIdx.x) >> 6;
    if (node >= nnodes) return;
    const int lane = threadIdx.x & 63;
    const bool active = lane < 60;
    const int slot = active ? (lane / 10) : 5;   // 0..5
    const int fi = lane % 10;
    const int fo = fi * 4;

    const int a = off[node];
    const int b = off[node + 1];

    f32x4 acc0 = {0,0,0,0}, acc1 = {0,0,0,0};

    int i = a;
    for (; i + 12 <= b; i += 12) {
        int s0 = ssrc[i + slot];
        int s1 = ssrc[i + 6 + slot];
        u16x4 v0 = *(const u16x4*)(T + (long)s0 * 40 + fo);
        u16x4 v1 = *(const u16x4*)(T + (long)s1 * 40 + fo);
        if (active) {
            #pragma unroll
            for (int j = 0; j < 4; ++j) {
                acc0[j] += bf16_to_f32(v0[j]);
                acc1[j] += bf16_to_f32(v1[j]);
            }
        }
    }
    for (; i < b; i += 6) {
        int e = i + slot;
        if (active && e < b) {
            int s = ssrc[e];
            u16x4 v = *(const u16x4*)(T + (long)s * 40 + fo);
            #pragma unroll
            for (int j = 0; j < 4; ++j) acc0[j] += bf16_to_f32(v[j]);
        }
    }
    f32x4 acc = acc0 + acc1;

    f32x4 tot = acc;
    #pragma unroll
    for (int d = 10; d <= 50; d += 10) {
        int srcl = fi + d;
        #pragma unroll
        for (int j = 0; j < 4; ++j) tot[j] += __shfl((float)acc[j], srcl);
    }

    if (lane < 10) {
        int deg = b - a;
        float scale = (deg > 0) ? (1.0f / (float)deg) : 0.f;
        f32x4 s4 = *(const f32x4*)(S + (long)node * 40 + fo);
        f32x4 r = s4 + tot * scale;
        if (RELU) {
            #pragma unroll
            for (int j = 0; j < 4; ++j) r[j] = fmaxf(r[j], 0.f);
        }
        *(f32x4*)(out + (long)node * 40 + fo) = r;
    }
}

// ---------------- launch ----------------

extern "C" void kernel_launch(void* const* d_in, const int* in_sizes, int n_in,
                              void* d_out, int out_size, void* d_ws, size_t ws_size,
                              hipStream_t stream) {
    const float* feat = (const float*)d_in[0];
    const int*   src  = (const int*)d_in[1];
    const int*   dst  = (const int*)d_in[2];
    const float* ws0  = (const float*)d_in[3];
    const float* wn0  = (const float*)d_in[4];
    const float* b0   = (const float*)d_in[5];
    const float* ws1  = (const float*)d_in[6];
    const float* wn1  = (const float*)d_in[7];
    const float* b1   = (const float*)d_in[8];
    const float* ws2  = (const float*)d_in[9];
    const float* wn2  = (const float*)d_in[10];
    const float* b2   = (const float*)d_in[11];

    const int N = N_NODES;
    const int NE = N_EDGES;
    const int NB = (N + 255) / 256;  // 196

    char* ws = (char*)d_ws;
    int*    offsets = (int*)(ws + 0);
    int*    cursor  = (int*)(ws + 200704);
    int*    degi    = (int*)(ws + 401408);
    int*    bsum    = (int*)(ws + 601600);
    int*    ssrc    = (int*)(ws + 603648);
    ushort* Bth0 = (ushort*)(ws + 200704);   // overlap cursor/degi, written after CSR build
    ushort* Btl0 = (ushort*)(ws + 266240);
    ushort* Bth1 = (ushort*)(ws + 331776);
    ushort* Btl1 = (ushort*)(ws + 397312);
    ushort* Bth2 = (ushort*)(ws + 462848);
    ushort* Btl2 = (ushort*)(ws + 483328);
    float*  hbuf = (float*)(ws + 3003904);   // 25.6 MB fp32
    float*  sbuf = (float*)(ws + 28603904);  // 25.6 MB fp32
    ushort* tbuf = (ushort*)(ws + 54203904); // 12.8 MB bf16

    // ---- CSR build ----
    hipMemsetAsync(degi, 0, (size_t)N * sizeof(int), stream);
    count_deg_kernel<<<(NE + 255) / 256, 256, 0, stream>>>(dst, degi, NE);
    block_sums_kernel<<<NB, 256, 0, stream>>>(degi, bsum, N);
    scatter_fused_kernel<<<NB, 256, 0, stream>>>(degi, bsum, offsets, cursor, N, NB);
    fill_csr_kernel<<<(NE + 255) / 256, 256, 0, stream>>>(src, dst, cursor, ssrc, NE);

    // ---- weight pre-convert (one dispatch) ----
    convert_all_w<<<592, 128, 0, stream>>>(ws0, wn0, ws1, wn1, ws2, wn2,
                                           Bth0, Btl0, Bth1, Btl1, Bth2, Btl2);

    const int gx = (N + 63) / 64;        // 782 GEMM blocks (64 rows each)
    const int ga = (N + 3) / 4;          // 12500 agg blocks (4 waves/block)

    // ---- layer 0 ----
    gemm_mfma_wide<<<gx, 256, 0, stream>>>(feat, Bth0, Btl0, b0, sbuf, tbuf, N);
    agg128_kernel<1><<<ga, 256, 0, stream>>>(sbuf, tbuf, offsets, ssrc, hbuf, N);

    // ---- layer 1 ----
    gemm_mfma_wide<<<gx, 256, 0, stream>>>(hbuf, Bth1, Btl1, b1, sbuf, tbuf, N);
    agg128_kernel<1><<<ga, 256, 0, stream>>>(sbuf, tbuf, offsets, ssrc, hbuf, N);

    // ---- layer 2 ----
    gemm_mfma_narrow<<<gx, 256, 0, stream>>>(hbuf, Bth2, Btl2, b2, sbuf, tbuf, N);
    agg40_kernel<0><<<ga, 256, 0, stream>>>(sbuf, tbuf, offsets, ssrc, (float*)d_out, N);
}